// Round 1
// baseline (58.205 us; speedup 1.0000x reference)
//
#include <hip/hip_runtime.h>
#include <math.h>

#define NB   512
#define CIN  64
#define COUT 64
#define NV   25
#define MID  8
#define NINT 32

// One block per batch element. All intermediates staged in LDS, fp32 throughout.
__global__ __launch_bounds__(256, 2)
void cga_fused(const float* __restrict__ x,
               const float* __restrict__ A_static,
               const float* __restrict__ w1, const float* __restrict__ b1,
               const float* __restrict__ w2, const float* __restrict__ b2,
               const float* __restrict__ w3, const float* __restrict__ b3,
               const float* __restrict__ diff_w, const float* __restrict__ diff_b,
               const float* __restrict__ edge_w, const float* __restrict__ edge_b,
               const float* __restrict__ att_w, const float* __restrict__ att_b,
               const float* __restrict__ cc1_w, const float* __restrict__ cc1_b,
               const float* __restrict__ bn_g, const float* __restrict__ bn_b,
               const float* __restrict__ bn_m, const float* __restrict__ bn_v,
               const float* __restrict__ cc2_w, const float* __restrict__ cc2_b,
               const float* __restrict__ cs_w, const float* __restrict__ cs_b,
               const float* __restrict__ alpha_p,
               float* __restrict__ out)
{
    const int b = blockIdx.x;
    const int t = threadIdx.x;

    __shared__ float xs[CIN * NV];        // input x for this batch      (1600)
    __shared__ float As[NV * NV];         // A_static                    (625)
    __shared__ float x1s[MID * NV];       // (200)
    __shared__ float x2s[MID * NV];       // (200)
    __shared__ float x3s[COUT * NV];      // (1600)
    __shared__ float Qs[MID * NV * NV];   // tanh(x1 outer x2 / 5)       (5000)
    __shared__ float Ps[MID * NV * NV];   // grouped-diff tanh           (5000)
    __shared__ float xatt[COUT * NV];     // (1600)
    __shared__ float gcn[COUT * NV];      // (1600)
    __shared__ float S3[COUT];            // row sums of x3
    __shared__ float xmean[COUT];
    __shared__ float hbuf[NINT];
    __shared__ float catt[COUT];
    __shared__ float satt[NV];

    const float* xb = x + (size_t)b * CIN * NV;

    // ---- stage input + A_static ----
    for (int i = t; i < CIN * NV; i += 256) xs[i] = xb[i];
    for (int i = t; i < NV * NV; i += 256)  As[i] = A_static[i];
    __syncthreads();

    // ---- x1, x2 (8x25 each) ----
    for (int i = t; i < 2 * MID * NV; i += 256) {
        int which = i / (MID * NV);
        int idx   = i % (MID * NV);
        int m = idx / NV, v = idx % NV;
        const float* w  = which ? w2 : w1;
        const float* bb = which ? b2 : b1;
        float acc = bb[m];
        for (int c = 0; c < CIN; ++c) acc += w[m * CIN + c] * xs[c * NV + v];
        if (which) x2s[idx] = acc; else x1s[idx] = acc;
    }
    // ---- x3 (64x25) ----
    for (int i = t; i < COUT * NV; i += 256) {
        int c = i / NV, v = i % NV;
        float acc = b3[c];
        for (int k = 0; k < CIN; ++k) acc += w3[c * CIN + k] * xs[k * NV + v];
        x3s[i] = acc;
    }
    __syncthreads();

    // ---- S3[c] = sum_v x3[c][v]  (sum over u identical) ----
    if (t < COUT) {
        float s = 0.f;
        for (int v = 0; v < NV; ++v) s += x3s[t * NV + v];
        S3[t] = s;
    }

    // ---- Q[m][u][v] = tanh(x1[m][u]*x2[m][v]/5)
    // ---- P[g][u][v] = tanh(grouped diff conv), concat channel layout:
    //      group g reads concat channels 2g,2g+1 of [d1_0..d1_7, d2_0..d2_7]
    for (int i = t; i < MID * NV * NV; i += 256) {
        int m = i / (NV * NV);
        int r = i % (NV * NV);
        int u = r / NV, v = r % NV;
        Qs[i] = tanhf(x1s[m * NV + u] * x2s[m * NV + v] * 0.2f);

        float dw0 = diff_w[2 * m], dw1 = diff_w[2 * m + 1];
        float a;
        if (m < 4) {
            int k0 = 2 * m, k1 = 2 * m + 1;   // d1 channels: x1[k][u]-x2[k][v]
            a = dw0 * (x1s[k0 * NV + u] - x2s[k0 * NV + v])
              + dw1 * (x1s[k1 * NV + u] - x2s[k1 * NV + v]);
        } else {
            int c0 = 2 * m - 8, c1 = 2 * m - 7; // d2 channels: x2[k][u]-x1[k][v]
            a = dw0 * (x2s[c0 * NV + u] - x1s[c0 * NV + v])
              + dw1 * (x2s[c1 * NV + u] - x1s[c1 * NV + v]);
        }
        Ps[i] = tanhf(a + diff_b[m]);
    }
    __syncthreads();

    // ---- x_att[c][v] = sum_m att_w[c,m] * (sum_u x3[c,u]*Q[m,u,v]) + att_b[c]*S3[c]
    for (int i = t; i < COUT * NV; i += 256) {
        int c = i / NV, v = i % NV;
        float acc = att_b[c] * S3[c];
        for (int m = 0; m < MID; ++m) {
            float am = 0.f;
            const float* qp = &Qs[m * NV * NV + v];
            const float* x3p = &x3s[c * NV];
            for (int u = 0; u < NV; ++u) am += x3p[u] * qp[u * NV];
            acc += att_w[c * MID + m] * am;
        }
        xatt[i] = acc;
    }
    __syncthreads();

    // ---- channel attention MLP ----
    if (t < COUT) {
        float s = 0.f;
        for (int v = 0; v < NV; ++v) s += xatt[t * NV + v];
        xmean[t] = s * (1.0f / NV);
    }
    __syncthreads();
    if (t < NINT) {
        float acc = cc1_b[t];
        for (int c = 0; c < COUT; ++c) acc += cc1_w[t * COUT + c] * xmean[c];
        acc = (acc - bn_m[t]) * (bn_g[t] * rsqrtf(bn_v[t] + 1e-5f)) + bn_b[t];
        acc = 0.5f * acc * (1.0f + erff(acc * 0.70710678118654752f)); // exact GELU
        hbuf[t] = acc;
    }
    __syncthreads();
    if (t < COUT) {
        float acc = cc2_b[t];
        for (int i = 0; i < NINT; ++i) acc += cc2_w[t * NINT + i] * hbuf[i];
        catt[t] = 1.0f / (1.0f + expf(-acc));
    }
    __syncthreads();

    const float alpha = alpha_p[0];

    // ---- x_gcn[c][u] = (sum_v As[u,v]*x3[c,v]
    //                    + alpha*(sum_m edge_w[c,m]*(sum_v P[m,u,v]*x3[c,v]) + edge_b[c]*S3[c]))
    //                    * catt[c]
    for (int i = t; i < COUT * NV; i += 256) {
        int c = i / NV, u = i % NV;
        const float* x3p = &x3s[c * NV];
        float accs = 0.f;
        const float* ap = &As[u * NV];
        for (int v = 0; v < NV; ++v) accs += ap[v] * x3p[v];
        float accd = edge_b[c] * S3[c];
        for (int m = 0; m < MID; ++m) {
            float am = 0.f;
            const float* pp = &Ps[m * NV * NV + u * NV];
            for (int v = 0; v < NV; ++v) am += pp[v] * x3p[v];
            accd += edge_w[c * MID + m] * am;
        }
        gcn[i] = (accs + alpha * accd) * catt[c];
    }
    __syncthreads();

    // ---- spatial attention ----
    if (t < NV) {
        float acc = cs_b[0];
        for (int c = 0; c < COUT; ++c) acc += cs_w[c] * gcn[c * NV + t];
        satt[t] = 1.0f / (1.0f + expf(-acc));
    }
    __syncthreads();

    // ---- out = gcn + xatt*satt + x ----
    float* ob = out + (size_t)b * COUT * NV;
    for (int i = t; i < COUT * NV; i += 256) {
        int v = i % NV;
        ob[i] = gcn[i] + xatt[i] * satt[v] + xs[i];
    }
}

extern "C" void kernel_launch(void* const* d_in, const int* in_sizes, int n_in,
                              void* d_out, int out_size, void* d_ws, size_t ws_size,
                              hipStream_t stream) {
    const float* x        = (const float*)d_in[0];
    const float* A_static = (const float*)d_in[1];
    const float* w1       = (const float*)d_in[2];
    const float* b1       = (const float*)d_in[3];
    const float* w2       = (const float*)d_in[4];
    const float* b2       = (const float*)d_in[5];
    const float* w3       = (const float*)d_in[6];
    const float* b3       = (const float*)d_in[7];
    const float* diff_w   = (const float*)d_in[8];
    const float* diff_b   = (const float*)d_in[9];
    const float* edge_w   = (const float*)d_in[10];
    const float* edge_b   = (const float*)d_in[11];
    const float* att_w    = (const float*)d_in[12];
    const float* att_b    = (const float*)d_in[13];
    const float* cc1_w    = (const float*)d_in[14];
    const float* cc1_b    = (const float*)d_in[15];
    const float* bn_g     = (const float*)d_in[16];
    const float* bn_b     = (const float*)d_in[17];
    const float* bn_m     = (const float*)d_in[18];
    const float* bn_v     = (const float*)d_in[19];
    const float* cc2_w    = (const float*)d_in[20];
    const float* cc2_b    = (const float*)d_in[21];
    const float* cs_w     = (const float*)d_in[22];
    const float* cs_b     = (const float*)d_in[23];
    const float* alpha    = (const float*)d_in[24];
    float* out = (float*)d_out;

    cga_fused<<<NB, 256, 0, stream>>>(x, A_static, w1, b1, w2, b2, w3, b3,
                                      diff_w, diff_b, edge_w, edge_b,
                                      att_w, att_b, cc1_w, cc1_b,
                                      bn_g, bn_b, bn_m, bn_v,
                                      cc2_w, cc2_b, cs_w, cs_b, alpha, out);
}